// Round 6
// baseline (1455.838 us; speedup 1.0000x reference)
//
#include <hip/hip_runtime.h>
#include <math.h>

// ---- weight buffer layout (floats) ----
// W1[16][5]@0  b1@80 | W2[32][16]@96  b2@608 | W3[16][35]@640 b3@1200 | W4[16]@1216 b4@1232
#define WTOT 1233

typedef __fp16 f16x8 __attribute__((ext_vector_type(8)));
typedef float f32x16 __attribute__((ext_vector_type(16)));

__device__ __forceinline__ float softplus_f(float x) {
  return fmaxf(x, 0.f) + log1pf(expf(-fabsf(x)));
}

struct PrepArgs {
  const float* wmu[4]; const float* wrho[4]; const float* epsw[4];
  const float* bmu[4]; const float* brho[4]; const float* epsb[4];
  float* out;
};

__global__ void prep_kernel(PrepArgs a) {
  const int wsz[4] = {80, 512, 560, 16};
  const int wof[4] = {0, 96, 640, 1216};
  const int bsz[4] = {16, 32, 16, 1};
  const int bof[4] = {80, 608, 1200, 1232};
  int b = blockIdx.x;
  if (b < 4) {
    const float* mu = a.wmu[b]; const float* rho = a.wrho[b]; const float* ep = a.epsw[b];
    float* o = a.out + wof[b];
    for (int i = threadIdx.x; i < wsz[b]; i += blockDim.x)
      o[i] = mu[i] + softplus_f(rho[i]) * ep[i];
  } else {
    int l = b - 4;
    const float* mu = a.bmu[l]; const float* rho = a.brho[l]; const float* ep = a.epsb[l];
    float* o = a.out + bof[l];
    for (int i = threadIdx.x; i < bsz[l]; i += blockDim.x)
      o[i] = mu[i] + softplus_f(rho[i]) * ep[i];
  }
}

__global__ void zero_kernel(int* __restrict__ p, int n) {
  int i = blockIdx.x * blockDim.x + threadIdx.x;
  if (i < n) p[i] = 0;
}

__global__ void zero4_kernel(uint4* __restrict__ p, int n4) {
  int i = blockIdx.x * blockDim.x + threadIdx.x;
  if (i < n4) p[i] = make_uint4(0u, 0u, 0u, 0u);
}

__global__ void count_kernel(const int* __restrict__ dst, int* __restrict__ deg, int E) {
  int e = blockIdx.x * blockDim.x + threadIdx.x;
  if (e < E) atomicAdd(&deg[dst[e]], 1);
}

// single-block exclusive scan; writes row_ptr[0..n] and cursor[0..n-1]
__global__ void scan_kernel(const int* __restrict__ deg, int* __restrict__ row_ptr,
                            int* __restrict__ cursor, int n) {
  __shared__ int wsum[16];
  __shared__ int woff[16];
  __shared__ int carry_s;
  __shared__ int total_s;
  int tid = threadIdx.x;
  int lane = tid & 63;
  int wid = tid >> 6;
  if (tid == 0) carry_s = 0;
  __syncthreads();
  for (int base = 0; base < n; base += 1024) {
    int i = base + tid;
    int v = (i < n) ? deg[i] : 0;
    int x = v;
#pragma unroll
    for (int off = 1; off < 64; off <<= 1) {
      int t = __shfl_up(x, off, 64);
      if (lane >= off) x += t;
    }
    if (lane == 63) wsum[wid] = x;
    __syncthreads();
    if (wid == 0) {
      int s = (lane < 16) ? wsum[lane] : 0;
#pragma unroll
      for (int off = 1; off < 16; off <<= 1) {
        int t = __shfl_up(s, off, 64);
        if (lane >= off) s += t;
      }
      if (lane < 16) woff[lane] = s - wsum[lane];
      if (lane == 15) total_s = s;
    }
    __syncthreads();
    int incl = x + woff[wid];
    int carry = carry_s;
    if (i < n) {
      int e = carry + incl - v;
      row_ptr[i] = e;
      cursor[i] = e;
    }
    __syncthreads();
    if (tid == 0) carry_s += total_s;
    __syncthreads();
  }
  if (threadIdx.x == 0) row_ptr[n] = carry_s;
}

// write packed edge records sorted by dst: (src, ea.x, ea.y, dst)
__global__ void fill_kernel(const int* __restrict__ src, const int* __restrict__ dst,
                            const float2* __restrict__ ea, int* __restrict__ cursor,
                            int4* __restrict__ erec, int E) {
  int e = blockIdx.x * blockDim.x + threadIdx.x;
  if (e >= E) return;
  int d = dst[e];
  int pos = atomicAdd(&cursor[d], 1);
  float2 a = ea[e];
  erec[pos] = make_int4(src[e], __float_as_int(a.x), __float_as_int(a.y), d);
}

__global__ void xprep_kernel(const float* __restrict__ x, float4* __restrict__ x4, int n) {
  int i = blockIdx.x * blockDim.x + threadIdx.x;
  if (i < n) x4[i] = make_float4(x[3 * i], x[3 * i + 1], x[3 * i + 2], 0.f);
}

// MFMA edge kernel: per wave, tiles of 32 dst-sorted edges.
// L1: A[m=edge 0..31][k=0..4] -> each lane's loaded inputs ARE its A-fragment
//     (lane&31 = m, lane>>5 selects k-block; k>=5 zero-padded).
// D1 (col=lane&31, row=(r&3)+8*(r>>2)+4*(lane>>5)) -> relu -> LDS [m][k] ->
// ds_read_b128 gives A2. L2 MFMA (K=16 exact). Bias via the C operand.
// Aggregation: readlane the 32 dsts (uniform), serial uniform-branch segmented
// max over sorted rows; run heads issue ONE wave-wide atomicMax (32 features).
__global__ __launch_bounds__(256) void edge_kernel(
    const float4* __restrict__ x4, const int4* __restrict__ erec,
    unsigned int* __restrict__ agg, const float* __restrict__ wg,
    int E, int N) {
  __shared__ __fp16 lds[4][32][32];  // per-wave 2KB transpose buffer
  const int l = threadIdx.x & 63;
  const int w = threadIdx.x >> 6;
  const int n = l & 31;   // feature / column, and edge row for A2 read
  const int h = l >> 5;   // k-block half

  // B fragments (resident for the whole grid-stride loop)
  f16x8 B1, B2;
#pragma unroll
  for (int j = 0; j < 8; j++) {
    int k = h * 8 + j;
    B1[j] = (__fp16)((n < 16 && k < 5) ? wg[n * 5 + k] : 0.f);
    B2[j] = (__fp16)(wg[96 + n * 16 + (k & 15)]);
  }
  float b1b = (n < 16) ? wg[80 + n] : 0.f;
  float b2b = wg[608 + n];
  f32x16 C1, C2;
#pragma unroll
  for (int r = 0; r < 16; r++) { C1[r] = b1b; C2[r] = b2b; }

  const int T = (E + 31) >> 5;
  const int nw = gridDim.x * 4;
  for (int t = blockIdx.x * 4 + w; t < T; t += nw) {
    const int tb = t << 5;
    int el = tb + n;  // both halves load the same 32 edges (dup loads hit L1)
    bool vld = el < E;
    int4 rec = erec[vld ? el : (E - 1)];
    if (!vld) rec.w = -1;
    float4 xs = x4[rec.x];

    f16x8 A1 = {};  // zero covers h==1 (k>=8) and k=5..7 padding
    if (h == 0) {
      A1[0] = (__fp16)xs.x; A1[1] = (__fp16)xs.y; A1[2] = (__fp16)xs.z;
      A1[3] = (__fp16)__int_as_float(rec.y);
      A1[4] = (__fp16)__int_as_float(rec.z);
    }
    f32x16 D1 = __builtin_amdgcn_mfma_f32_32x32x16_f16(A1, B1, C1, 0, 0, 0);

    // relu + transpose (col-major acc -> row-major [m][k]) via per-wave LDS
#pragma unroll
    for (int r = 0; r < 16; r++) {
      int m = (r & 3) + 8 * (r >> 2) + 4 * h;
      lds[w][m][n] = (__fp16)fmaxf(D1[r], 0.f);
    }
    __builtin_amdgcn_wave_barrier();
    __builtin_amdgcn_s_waitcnt(0);
    __builtin_amdgcn_wave_barrier();
    f16x8 A2 = *(const f16x8*)&lds[w][n][h * 8];

    f32x16 D2 = __builtin_amdgcn_mfma_f32_32x32x16_f16(A2, B2, C2, 0, 0, 0);
    float own[16], oth[16];
#pragma unroll
    for (int r = 0; r < 16; r++) {
      own[r] = fmaxf(D2[r], 0.f);
      oth[r] = __shfl_xor(own[r], 32, 64);
    }

    // serial segmented max over sorted rows m=0..31; dst uniform via readlane
    float run = 0.f;
    int cur = -1;
#pragma unroll
    for (int m = 0; m < 32; m++) {
      int r = (m & 3) + 4 * (m >> 3);
      bool ownHalf = (((m >> 2) & 1) == h);
      float v = ownHalf ? own[r] : oth[r];
      int d = __builtin_amdgcn_readlane(rec.w, m);
      if (m == 0) {
        run = v; cur = d;
      } else if (d != cur) {  // uniform branch
        if (cur >= 0 && h == 0)
          atomicMax(agg + (size_t)n * N + cur, __float_as_uint(run));
        run = v; cur = d;
      } else {
        run = fmaxf(run, v);
      }
    }
    if (cur >= 0 && h == 0)
      atomicMax(agg + (size_t)n * N + cur, __float_as_uint(run));
  }
}

// node-parallel: agg is [32][N] (feature-major, coalesced). Read, re-zero for
// the next iteration, apply node MLP + sigmoid, write next x (and final out).
__global__ __launch_bounds__(256) void node_kernel(
    const float4* __restrict__ x4in, float4* __restrict__ x4out,
    float* __restrict__ outFinal, unsigned int* __restrict__ agg,
    const float* __restrict__ wg, int n) {
  int nid = blockIdx.x * blockDim.x + threadIdx.x;
  if (nid >= n) return;
  float av[32];
#pragma unroll
  for (int o = 0; o < 32; o++) {
    av[o] = __uint_as_float(agg[(size_t)o * n + nid]);
    agg[(size_t)o * n + nid] = 0u;
  }
  float4 xs = x4in[nid];
  float h[16];
#pragma unroll
  for (int o = 0; o < 16; o++) {
    float sa = wg[1200 + o];  // b3
    sa = fmaf(wg[640 + o * 35 + 0], xs.x, sa);
    sa = fmaf(wg[640 + o * 35 + 1], xs.y, sa);
    sa = fmaf(wg[640 + o * 35 + 2], xs.z, sa);
#pragma unroll
    for (int k = 0; k < 32; k++) sa = fmaf(wg[640 + o * 35 + 3 + k], av[k], sa);
    h[o] = fmaxf(sa, 0.f);
  }
  float z = wg[1232];  // b4
#pragma unroll
  for (int k = 0; k < 16; k++) z = fmaf(wg[1216 + k], h[k], z);
  float comb = 1.f / (1.f + expf(-z));
  x4out[nid] = make_float4(xs.x, xs.y, comb, 0.f);
  if (outFinal) {
    outFinal[3 * nid] = xs.x;
    outFinal[3 * nid + 1] = xs.y;
    outFinal[3 * nid + 2] = comb;
  }
}

extern "C" void kernel_launch(void* const* d_in, const int* in_sizes, int n_in,
                              void* d_out, int out_size, void* d_ws, size_t ws_size,
                              hipStream_t stream) {
  const float* x = (const float*)d_in[0];
  const float* ea = (const float*)d_in[1];
  const int* eidx = (const int*)d_in[2];
  const int N = in_sizes[0] / 3;
  const int E = in_sizes[1] / 2;
  const int* src = eidx;
  const int* dst = eidx + E;

  // ---- workspace carve-up ----
  char* p = (char*)d_ws;
  size_t off = 0;
  auto alloc = [&](size_t bytes) -> char* {
    char* r = p + off;
    off = (off + bytes + 255) & ~(size_t)255;
    return r;
  };
  float* wbuf = (float*)alloc((size_t)WTOT * 4);
  int* deg = (int*)alloc((size_t)N * 4);
  int* row = (int*)alloc(((size_t)N + 1) * 4);
  int* cursor = (int*)alloc((size_t)N * 4);
  int4* erec = (int4*)alloc((size_t)E * 16);
  unsigned int* agg = (unsigned int*)alloc((size_t)N * 32 * 4);  // [32][N]
  float4* x4a = (float4*)alloc((size_t)N * 16);
  float4* x4b = (float4*)alloc((size_t)N * 16);
  (void)ws_size;

  PrepArgs pa;
  for (int l = 0; l < 4; l++) {
    pa.wmu[l] = (const float*)d_in[3 + 6 * l + 0];
    pa.wrho[l] = (const float*)d_in[3 + 6 * l + 1];
    pa.bmu[l] = (const float*)d_in[3 + 6 * l + 2];
    pa.brho[l] = (const float*)d_in[3 + 6 * l + 3];
    pa.epsw[l] = (const float*)d_in[3 + 6 * l + 4];
    pa.epsb[l] = (const float*)d_in[3 + 6 * l + 5];
  }
  pa.out = wbuf;

  const int TB = 256;
  auto blocks = [&](int n) { return dim3((n + TB - 1) / TB); };

  zero_kernel<<<blocks(N), dim3(TB), 0, stream>>>(deg, N);
  prep_kernel<<<dim3(8), dim3(128), 0, stream>>>(pa);
  count_kernel<<<blocks(E), dim3(TB), 0, stream>>>(dst, deg, E);
  scan_kernel<<<dim3(1), dim3(1024), 0, stream>>>(deg, row, cursor, N);
  fill_kernel<<<blocks(E), dim3(TB), 0, stream>>>(src, dst, (const float2*)ea, cursor,
                                                  erec, E);
  xprep_kernel<<<blocks(N), dim3(TB), 0, stream>>>(x, x4a, N);
  int n4 = N * 8;  // 32*N uints as uint4
  zero4_kernel<<<blocks(n4), dim3(TB), 0, stream>>>((uint4*)agg, n4);

  float* outp = (float*)d_out;
  const int EB = 2048;  // edge kernel blocks (4 waves each), grid-stride over tiles
  // iter 1
  edge_kernel<<<dim3(EB), dim3(TB), 0, stream>>>(x4a, erec, agg, wbuf, E, N);
  node_kernel<<<blocks(N), dim3(TB), 0, stream>>>(x4a, x4b, nullptr, agg, wbuf, N);
  // iter 2
  edge_kernel<<<dim3(EB), dim3(TB), 0, stream>>>(x4b, erec, agg, wbuf, E, N);
  node_kernel<<<blocks(N), dim3(TB), 0, stream>>>(x4b, x4a, nullptr, agg, wbuf, N);
  // iter 3
  edge_kernel<<<dim3(EB), dim3(TB), 0, stream>>>(x4a, erec, agg, wbuf, E, N);
  node_kernel<<<blocks(N), dim3(TB), 0, stream>>>(x4a, x4b, outp, agg, wbuf, N);
}

// Round 7
// 1423.697 us; speedup vs baseline: 1.0226x; 1.0226x over previous
//
#include <hip/hip_runtime.h>
#include <math.h>

// ---- weight buffer layout ----
// fp32 section (dwords 0..1232):
// W1[16][5]@0 b1@80 | W2[32][16]@96 b2@608 | W3[16][35]@640 b3@1200 | W4[16]@1216 b4@1232
// packed fp16 section (uint view at dword offset 1280):
// w1a[16]@0 (w[o5+0],w[o5+1]) | w1b[16]@16 (w[o5+2],0) | w1c[16]@32 (w[o5+3],w[o5+4])
// w2pk[32][8]@48 | b1f[16]@304 (fp32) | b2f[32]@320 (fp32)   -- total 352 dwords
#define WTOT  1233
#define PKOFS 1280
#define PKTOT 352

typedef __fp16 h2 __attribute__((ext_vector_type(2)));

__device__ __forceinline__ h2 u2h(unsigned int u) { return __builtin_bit_cast(h2, u); }
__device__ __forceinline__ unsigned int h2u(h2 h) { return __builtin_bit_cast(unsigned int, h); }
#define DOT2(a, b, c) __builtin_amdgcn_fdot2((a), (b), (c), false)

__device__ __forceinline__ float softplus_f(float x) {
  return fmaxf(x, 0.f) + log1pf(expf(-fabsf(x)));
}

struct PrepArgs {
  const float* wmu[4]; const float* wrho[4]; const float* epsw[4];
  const float* bmu[4]; const float* brho[4]; const float* epsb[4];
  float* out;
};

__global__ void prep_kernel(PrepArgs a) {
  const int wsz[4] = {80, 512, 560, 16};
  const int wof[4] = {0, 96, 640, 1216};
  const int bsz[4] = {16, 32, 16, 1};
  const int bof[4] = {80, 608, 1200, 1232};
  int b = blockIdx.x;
  if (b < 4) {
    const float* mu = a.wmu[b]; const float* rho = a.wrho[b]; const float* ep = a.epsw[b];
    float* o = a.out + wof[b];
    for (int i = threadIdx.x; i < wsz[b]; i += blockDim.x)
      o[i] = mu[i] + softplus_f(rho[i]) * ep[i];
  } else {
    int l = b - 4;
    const float* mu = a.bmu[l]; const float* rho = a.brho[l]; const float* ep = a.epsb[l];
    float* o = a.out + bof[l];
    for (int i = threadIdx.x; i < bsz[l]; i += blockDim.x)
      o[i] = mu[i] + softplus_f(rho[i]) * ep[i];
  }
}

// pack fp16 weight pairs from the fp32 section (runs after prep_kernel)
__global__ void pack_kernel(const float* __restrict__ wg, unsigned int* __restrict__ wp) {
  int t = threadIdx.x;
  if (t < 16) {
    wp[t]      = h2u(h2{(__fp16)wg[t * 5 + 0], (__fp16)wg[t * 5 + 1]});
    wp[16 + t] = h2u(h2{(__fp16)wg[t * 5 + 2], (__fp16)0.f});
    wp[32 + t] = h2u(h2{(__fp16)wg[t * 5 + 3], (__fp16)wg[t * 5 + 4]});
    ((float*)wp)[304 + t] = wg[80 + t];
  }
  if (t < 32) {
    ((float*)wp)[320 + t] = wg[608 + t];
    for (int j = 0; j < 8; j++)
      wp[48 + t * 8 + j] =
          h2u(h2{(__fp16)wg[96 + t * 16 + 2 * j], (__fp16)wg[96 + t * 16 + 2 * j + 1]});
  }
}

__global__ void zero_kernel(int* __restrict__ p, int n) {
  int i = blockIdx.x * blockDim.x + threadIdx.x;
  if (i < n) p[i] = 0;
}

__global__ void zero4_kernel(uint4* __restrict__ p, int n4) {
  int i = blockIdx.x * blockDim.x + threadIdx.x;
  if (i < n4) p[i] = make_uint4(0u, 0u, 0u, 0u);
}

__global__ void count_kernel(const int* __restrict__ dst, int* __restrict__ deg, int E) {
  int e = blockIdx.x * blockDim.x + threadIdx.x;
  if (e < E) atomicAdd(&deg[dst[e]], 1);
}

// ---- 3-phase exclusive scan ----
__global__ void scanA_kernel(const int* __restrict__ deg, int* __restrict__ part, int n) {
  __shared__ int ws[16];
  int tid = threadIdx.x;
  int i = blockIdx.x * 1024 + tid;
  int v = (i < n) ? deg[i] : 0;
#pragma unroll
  for (int off = 32; off >= 1; off >>= 1) v += __shfl_down(v, off, 64);
  if ((tid & 63) == 0) ws[tid >> 6] = v;
  __syncthreads();
  if (tid == 0) {
    int s = 0;
#pragma unroll
    for (int k = 0; k < 16; k++) s += ws[k];
    part[blockIdx.x] = s;
  }
}

__global__ void scanB_kernel(int* __restrict__ part, int P) {
  int lane = threadIdx.x;  // single wave of 64
  int carry = 0;
  for (int base = 0; base < P; base += 64) {
    int i = base + lane;
    int v = (i < P) ? part[i] : 0;
    int x = v;
#pragma unroll
    for (int off = 1; off < 64; off <<= 1) {
      int t = __shfl_up(x, off, 64);
      if (lane >= off) x += t;
    }
    if (i < P) part[i] = carry + x - v;  // exclusive
    carry += __shfl(x, 63, 64);
  }
}

__global__ void scanC_kernel(const int* __restrict__ deg, const int* __restrict__ part,
                             int* __restrict__ cursor, int n) {
  __shared__ int wsum[16];
  __shared__ int woff[16];
  int tid = threadIdx.x, lane = tid & 63, wid = tid >> 6;
  int i = blockIdx.x * 1024 + tid;
  int v = (i < n) ? deg[i] : 0;
  int x = v;
#pragma unroll
  for (int off = 1; off < 64; off <<= 1) {
    int t = __shfl_up(x, off, 64);
    if (lane >= off) x += t;
  }
  if (lane == 63) wsum[wid] = x;
  __syncthreads();
  if (wid == 0) {
    int s = (lane < 16) ? wsum[lane] : 0;
#pragma unroll
    for (int off = 1; off < 16; off <<= 1) {
      int t = __shfl_up(s, off, 64);
      if (lane >= off) s += t;
    }
    if (lane < 16) woff[lane] = s - wsum[lane];
  }
  __syncthreads();
  if (i < n) cursor[i] = part[blockIdx.x] + woff[wid] + x - v;
}

// write packed edge records sorted by dst: (src, dst, pk(ea0,ea1), 0)
__global__ void fill_kernel(const int* __restrict__ src, const int* __restrict__ dst,
                            const float2* __restrict__ ea, int* __restrict__ cursor,
                            int4* __restrict__ erec, int E) {
  int e = blockIdx.x * blockDim.x + threadIdx.x;
  if (e >= E) return;
  int d = dst[e];
  int pos = atomicAdd(&cursor[d], 1);
  float2 a = ea[e];
  h2 ap = __builtin_amdgcn_cvt_pkrtz(a.x, a.y);
  erec[pos] = make_int4(src[e], d, (int)h2u(ap), 0);
}

__global__ void xprep_kernel(const float* __restrict__ x, uint2* __restrict__ xpk, int n) {
  int i = blockIdx.x * blockDim.x + threadIdx.x;
  if (i < n) {
    h2 a = __builtin_amdgcn_cvt_pkrtz(x[3 * i], x[3 * i + 1]);
    h2 b = __builtin_amdgcn_cvt_pkrtz(x[3 * i + 2], 0.f);
    xpk[i] = make_uint2(h2u(a), h2u(b));
  }
}

__device__ __forceinline__ void flushRun(unsigned int* __restrict__ agg, int d,
                                         const unsigned int* run) {
  unsigned int* a = agg + (size_t)d * 32;
#pragma unroll
  for (int i = 0; i < 16; i++) {
    h2 h = u2h(run[i]);
    atomicMax(a + 2 * i, __float_as_uint((float)h.x));
    atomicMax(a + 2 * i + 1, __float_as_uint((float)h.y));
  }
}

// edge-parallel, K=4 dst-sorted edges per thread. fp16 dot2 MLP, per-thread
// segmented merge, fp16-packed wave segmented max, head lanes flush.
__global__ __launch_bounds__(256) void edge_kernel(
    const uint2* __restrict__ xpk, const int4* __restrict__ erec,
    unsigned int* __restrict__ agg, const float* __restrict__ wg, int E) {
  const unsigned int* wp = (const unsigned int*)(wg + PKOFS);
  const float* bf = (const float*)wp;
  int t0 = (blockIdx.x * blockDim.x + threadIdx.x) * 4;
  int lane = threadIdx.x & 63;

  int4 rec[4];
  uint2 xs[4];
  bool vld[4];
#pragma unroll
  for (int j = 0; j < 4; j++) {
    int e = t0 + j;
    vld[j] = e < E;
    rec[j] = erec[vld[j] ? e : 0];
  }
#pragma unroll
  for (int j = 0; j < 4; j++) xs[j] = xpk[rec[j].x];

  unsigned int run[16];
  int cur = -1;
#pragma unroll
  for (int j = 0; j < 4; j++) {
    // ---- edge MLP ----
    h2 p01 = u2h(xs[j].x);
    h2 p2 = u2h(xs[j].y);
    h2 pea = u2h((unsigned int)rec[j].z);
    unsigned int m1p[8];
#pragma unroll
    for (int o2 = 0; o2 < 8; o2++) {
      int oA = 2 * o2, oB = oA + 1;
      float sA = DOT2(p01, u2h(wp[oA]),
                  DOT2(p2, u2h(wp[16 + oA]),
                  DOT2(pea, u2h(wp[32 + oA]), bf[304 + oA])));
      float sB = DOT2(p01, u2h(wp[oB]),
                  DOT2(p2, u2h(wp[16 + oB]),
                  DOT2(pea, u2h(wp[32 + oB]), bf[304 + oB])));
      m1p[o2] = h2u(__builtin_amdgcn_cvt_pkrtz(fmaxf(sA, 0.f), fmaxf(sB, 0.f)));
    }
    unsigned int pk[16];
#pragma unroll
    for (int o2 = 0; o2 < 16; o2++) {
      int oA = 2 * o2, oB = oA + 1;
      float sA = bf[320 + oA], sB = bf[320 + oB];
#pragma unroll
      for (int k = 0; k < 8; k++) {
        sA = DOT2(u2h(m1p[k]), u2h(wp[48 + oA * 8 + k]), sA);
        sB = DOT2(u2h(m1p[k]), u2h(wp[48 + oB * 8 + k]), sB);
      }
      pk[o2] = h2u(__builtin_amdgcn_cvt_pkrtz(fmaxf(sA, 0.f), fmaxf(sB, 0.f)));
    }
    // ---- per-thread segmented merge ----
    int dj = vld[j] ? rec[j].y : -1;
    if (j == 0) {
      cur = dj;
#pragma unroll
      for (int i = 0; i < 16; i++) run[i] = pk[i];
    } else if (dj == cur) {
#pragma unroll
      for (int i = 0; i < 16; i++)
        run[i] = h2u(__builtin_elementwise_max(u2h(run[i]), u2h(pk[i])));
    } else {
      if (cur >= 0) flushRun(agg, cur, run);
      cur = dj;
#pragma unroll
      for (int i = 0; i < 16; i++) run[i] = pk[i];
    }
  }

  // ---- wave segmented max over per-thread tail runs ----
#pragma unroll
  for (int off = 1; off < 64; off <<= 1) {
    int c2 = __shfl_down(cur, off, 64);
    unsigned int msk = ((lane + off < 64) && (c2 == cur) && (cur >= 0)) ? 0xFFFFFFFFu : 0u;
#pragma unroll
    for (int i = 0; i < 16; i++) {
      unsigned int v2 = __shfl_down(run[i], off, 64) & msk;
      run[i] = h2u(__builtin_elementwise_max(u2h(run[i]), u2h(v2)));
    }
  }
  int cprev = __shfl_up(cur, 1, 64);
  bool head = (cur >= 0) && (lane == 0 || cprev != cur);
  if (head) flushRun(agg, cur, run);
}

// node-parallel: read agg[nid][0..31], re-zero for next iter, node MLP + sigmoid.
// x0,x1 come from the pristine fp32 input (exact); x2 from comb ping-pong.
__global__ __launch_bounds__(256) void node_kernel(
    const float* __restrict__ x, const float* __restrict__ cin,
    float* __restrict__ cout, uint2* __restrict__ xpk,
    float* __restrict__ outFinal, unsigned int* __restrict__ agg,
    const float* __restrict__ wg, int n) {
  int nid = blockIdx.x * blockDim.x + threadIdx.x;
  if (nid >= n) return;
  unsigned int* a = agg + (size_t)nid * 32;
  float av[32];
#pragma unroll
  for (int o = 0; o < 32; o += 4) {
    uint4 u = *(const uint4*)(a + o);
    av[o] = __uint_as_float(u.x);
    av[o + 1] = __uint_as_float(u.y);
    av[o + 2] = __uint_as_float(u.z);
    av[o + 3] = __uint_as_float(u.w);
    *(uint4*)(a + o) = make_uint4(0u, 0u, 0u, 0u);
  }
  float x0 = x[3 * nid], x1 = x[3 * nid + 1];
  float x2 = cin ? cin[nid] : x[3 * nid + 2];
  float h[16];
#pragma unroll
  for (int o = 0; o < 16; o++) {
    float sa = wg[1200 + o];  // b3
    sa = fmaf(wg[640 + o * 35 + 0], x0, sa);
    sa = fmaf(wg[640 + o * 35 + 1], x1, sa);
    sa = fmaf(wg[640 + o * 35 + 2], x2, sa);
#pragma unroll
    for (int k = 0; k < 32; k++) sa = fmaf(wg[640 + o * 35 + 3 + k], av[k], sa);
    h[o] = fmaxf(sa, 0.f);
  }
  float z = wg[1232];  // b4
#pragma unroll
  for (int k = 0; k < 16; k++) z = fmaf(wg[1216 + k], h[k], z);
  float comb = 1.f / (1.f + expf(-z));
  cout[nid] = comb;
  ((unsigned int*)xpk)[2 * nid + 1] = h2u(__builtin_amdgcn_cvt_pkrtz(comb, 0.f));
  if (outFinal) {
    outFinal[3 * nid] = x0;
    outFinal[3 * nid + 1] = x1;
    outFinal[3 * nid + 2] = comb;
  }
}

extern "C" void kernel_launch(void* const* d_in, const int* in_sizes, int n_in,
                              void* d_out, int out_size, void* d_ws, size_t ws_size,
                              hipStream_t stream) {
  const float* x = (const float*)d_in[0];
  const float* ea = (const float*)d_in[1];
  const int* eidx = (const int*)d_in[2];
  const int N = in_sizes[0] / 3;
  const int E = in_sizes[1] / 2;
  const int* src = eidx;
  const int* dst = eidx + E;
  const int P = (N + 1023) / 1024;

  // ---- workspace carve-up ----
  char* p = (char*)d_ws;
  size_t off = 0;
  auto alloc = [&](size_t bytes) -> char* {
    char* r = p + off;
    off = (off + bytes + 255) & ~(size_t)255;
    return r;
  };
  float* wbuf = (float*)alloc((size_t)(PKOFS + PKTOT) * 4);
  int* deg = (int*)alloc((size_t)N * 4);
  int* part = (int*)alloc((size_t)P * 4);
  int* cursor = (int*)alloc((size_t)N * 4);
  int4* erec = (int4*)alloc((size_t)E * 16);
  unsigned int* agg = (unsigned int*)alloc((size_t)N * 32 * 4);  // [N][32]
  uint2* xpk = (uint2*)alloc((size_t)N * 8);
  float* bufA = (float*)alloc((size_t)N * 4);
  float* bufB = (float*)alloc((size_t)N * 4);
  (void)ws_size;

  PrepArgs pa;
  for (int l = 0; l < 4; l++) {
    pa.wmu[l] = (const float*)d_in[3 + 6 * l + 0];
    pa.wrho[l] = (const float*)d_in[3 + 6 * l + 1];
    pa.bmu[l] = (const float*)d_in[3 + 6 * l + 2];
    pa.brho[l] = (const float*)d_in[3 + 6 * l + 3];
    pa.epsw[l] = (const float*)d_in[3 + 6 * l + 4];
    pa.epsb[l] = (const float*)d_in[3 + 6 * l + 5];
  }
  pa.out = wbuf;

  const int TB = 256;
  auto blocks = [&](int n) { return dim3((n + TB - 1) / TB); };

  zero_kernel<<<blocks(N), dim3(TB), 0, stream>>>(deg, N);
  prep_kernel<<<dim3(8), dim3(128), 0, stream>>>(pa);
  pack_kernel<<<dim3(1), dim3(64), 0, stream>>>(wbuf, (unsigned int*)(wbuf + PKOFS));
  count_kernel<<<blocks(E), dim3(TB), 0, stream>>>(dst, deg, E);
  scanA_kernel<<<dim3(P), dim3(1024), 0, stream>>>(deg, part, N);
  scanB_kernel<<<dim3(1), dim3(64), 0, stream>>>(part, P);
  scanC_kernel<<<dim3(P), dim3(1024), 0, stream>>>(deg, part, cursor, N);
  fill_kernel<<<blocks(E), dim3(TB), 0, stream>>>(src, dst, (const float2*)ea, cursor,
                                                  erec, E);
  xprep_kernel<<<blocks(N), dim3(TB), 0, stream>>>(x, xpk, N);
  int n4 = N * 8;  // N*32 uints as uint4
  zero4_kernel<<<blocks(n4), dim3(TB), 0, stream>>>((uint4*)agg, n4);

  float* outp = (float*)d_out;
  int eb = (E + TB * 4 - 1) / (TB * 4);
  // iter 1
  edge_kernel<<<dim3(eb), dim3(TB), 0, stream>>>(xpk, erec, agg, wbuf, E);
  node_kernel<<<blocks(N), dim3(TB), 0, stream>>>(x, nullptr, bufA, xpk, nullptr, agg, wbuf, N);
  // iter 2
  edge_kernel<<<dim3(eb), dim3(TB), 0, stream>>>(xpk, erec, agg, wbuf, E);
  node_kernel<<<blocks(N), dim3(TB), 0, stream>>>(x, bufA, bufB, xpk, nullptr, agg, wbuf, N);
  // iter 3
  edge_kernel<<<dim3(eb), dim3(TB), 0, stream>>>(xpk, erec, agg, wbuf, E);
  node_kernel<<<blocks(N), dim3(TB), 0, stream>>>(x, bufB, bufA, xpk, outp, agg, wbuf, N);
}

// Round 8
// 1408.627 us; speedup vs baseline: 1.0335x; 1.0107x over previous
//
#include <hip/hip_runtime.h>
#include <math.h>

// ---- weight buffer layout ----
// fp32 section (dwords 0..1232):
// W1[16][5]@0 b1@80 | W2[32][16]@96 b2@608 | W3[16][35]@640 b3@1200 | W4[16]@1216 b4@1232
// packed fp16 section (uint view at dword offset 1280):
// w1a[16]@0 (w[o5+0],w[o5+1]) | w1b[16]@16 (w[o5+2],0) | w1c[16]@32 (w[o5+3],w[o5+4])
// w2pk[32][8]@48 | b1f[16]@304 (fp32) | b2f[32]@320 (fp32)   -- total 352 dwords
#define WTOT  1233
#define PKOFS 1280
#define PKTOT 352

typedef __fp16 h2 __attribute__((ext_vector_type(2)));

__device__ __forceinline__ h2 u2h(unsigned int u) { return __builtin_bit_cast(h2, u); }
__device__ __forceinline__ unsigned int h2u(h2 h) { return __builtin_bit_cast(unsigned int, h); }
#define DOT2(a, b, c) __builtin_amdgcn_fdot2((a), (b), (c), false)

__device__ __forceinline__ float softplus_f(float x) {
  return fmaxf(x, 0.f) + log1pf(expf(-fabsf(x)));
}

struct PrepArgs {
  const float* wmu[4]; const float* wrho[4]; const float* epsw[4];
  const float* bmu[4]; const float* brho[4]; const float* epsb[4];
  float* out;
};

// single block 1024: sample all weights, then pack fp16 section
__global__ void prep_all_kernel(PrepArgs a) {
  const int wsz[4] = {80, 512, 560, 16};
  const int wof[4] = {0, 96, 640, 1216};
  const int bsz[4] = {16, 32, 16, 1};
  const int bof[4] = {80, 608, 1200, 1232};
  float* wg = a.out;
  int tid = threadIdx.x;
#pragma unroll
  for (int l = 0; l < 4; l++) {
    for (int i = tid; i < wsz[l]; i += 1024)
      wg[wof[l] + i] = a.wmu[l][i] + softplus_f(a.wrho[l][i]) * a.epsw[l][i];
    for (int i = tid; i < bsz[l]; i += 1024)
      wg[bof[l] + i] = a.bmu[l][i] + softplus_f(a.brho[l][i]) * a.epsb[l][i];
  }
  __syncthreads();
  unsigned int* wp = (unsigned int*)(wg + PKOFS);
  int t = tid;
  if (t < 16) {
    wp[t]      = h2u(h2{(__fp16)wg[t * 5 + 0], (__fp16)wg[t * 5 + 1]});
    wp[16 + t] = h2u(h2{(__fp16)wg[t * 5 + 2], (__fp16)0.f});
    wp[32 + t] = h2u(h2{(__fp16)wg[t * 5 + 3], (__fp16)wg[t * 5 + 4]});
    ((float*)wp)[304 + t] = wg[80 + t];
  }
  if (t < 32) {
    ((float*)wp)[320 + t] = wg[608 + t];
    for (int j = 0; j < 8; j++)
      wp[48 + t * 8 + j] =
          h2u(h2{(__fp16)wg[96 + t * 16 + 2 * j], (__fp16)wg[96 + t * 16 + 2 * j + 1]});
  }
}

__global__ void zero_kernel(int* __restrict__ p, int n) {
  int i = blockIdx.x * blockDim.x + threadIdx.x;
  if (i < n) p[i] = 0;
}

__global__ void count_kernel(const int* __restrict__ dst, int* __restrict__ deg, int E) {
  int e = blockIdx.x * blockDim.x + threadIdx.x;
  if (e < E) atomicAdd(&deg[dst[e]], 1);
}

// ---- 3-phase exclusive scan ----
__global__ void scanA_kernel(const int* __restrict__ deg, int* __restrict__ part, int n) {
  __shared__ int ws[16];
  int tid = threadIdx.x;
  int i = blockIdx.x * 1024 + tid;
  int v = (i < n) ? deg[i] : 0;
#pragma unroll
  for (int off = 32; off >= 1; off >>= 1) v += __shfl_down(v, off, 64);
  if ((tid & 63) == 0) ws[tid >> 6] = v;
  __syncthreads();
  if (tid == 0) {
    int s = 0;
#pragma unroll
    for (int k = 0; k < 16; k++) s += ws[k];
    part[blockIdx.x] = s;
  }
}

__global__ void scanB_kernel(int* __restrict__ part, int P) {
  int lane = threadIdx.x;  // single wave of 64
  int carry = 0;
  for (int base = 0; base < P; base += 64) {
    int i = base + lane;
    int v = (i < P) ? part[i] : 0;
    int x = v;
#pragma unroll
    for (int off = 1; off < 64; off <<= 1) {
      int t = __shfl_up(x, off, 64);
      if (lane >= off) x += t;
    }
    if (i < P) part[i] = carry + x - v;  // exclusive
    carry += __shfl(x, 63, 64);
  }
}

__global__ void scanC_kernel(const int* __restrict__ deg, const int* __restrict__ part,
                             int* __restrict__ cursor, int n) {
  __shared__ int wsum[16];
  __shared__ int woff[16];
  int tid = threadIdx.x, lane = tid & 63, wid = tid >> 6;
  int i = blockIdx.x * 1024 + tid;
  int v = (i < n) ? deg[i] : 0;
  int x = v;
#pragma unroll
  for (int off = 1; off < 64; off <<= 1) {
    int t = __shfl_up(x, off, 64);
    if (lane >= off) x += t;
  }
  if (lane == 63) wsum[wid] = x;
  __syncthreads();
  if (wid == 0) {
    int s = (lane < 16) ? wsum[lane] : 0;
#pragma unroll
    for (int off = 1; off < 16; off <<= 1) {
      int t = __shfl_up(s, off, 64);
      if (lane >= off) s += t;
    }
    if (lane < 16) woff[lane] = s - wsum[lane];
  }
  __syncthreads();
  if (i < n) cursor[i] = part[blockIdx.x] + woff[wid] + x - v;
}

// write packed edge records sorted by dst: (src, dst, pk(ea0,ea1), 0)
__global__ void fill_kernel(const int* __restrict__ src, const int* __restrict__ dst,
                            const float2* __restrict__ ea, int* __restrict__ cursor,
                            int4* __restrict__ erec, int E) {
  int e = blockIdx.x * blockDim.x + threadIdx.x;
  if (e >= E) return;
  int d = dst[e];
  int pos = atomicAdd(&cursor[d], 1);
  float2 a = ea[e];
  h2 ap = __builtin_amdgcn_cvt_pkrtz(a.x, a.y);
  erec[pos] = make_int4(src[e], d, (int)h2u(ap), 0);
}

// fused: zero agg (as uint4, n4 = 8*N entries) + pack x to fp16 pairs
__global__ void init_kernel(const float* __restrict__ x, uint2* __restrict__ xpk,
                            uint4* __restrict__ aggv, int n, int n4) {
  int i = blockIdx.x * blockDim.x + threadIdx.x;
  if (i < n4) aggv[i] = make_uint4(0u, 0u, 0u, 0u);
  if (i < n) {
    h2 a = __builtin_amdgcn_cvt_pkrtz(x[3 * i], x[3 * i + 1]);
    h2 b = __builtin_amdgcn_cvt_pkrtz(x[3 * i + 2], 0.f);
    xpk[i] = make_uint2(h2u(a), h2u(b));
  }
}

__device__ __forceinline__ void flushRun(unsigned int* __restrict__ agg, int d,
                                         const unsigned int* run) {
  unsigned int* a = agg + (size_t)d * 32;
#pragma unroll
  for (int i = 0; i < 16; i++) {
    h2 h = u2h(run[i]);
    atomicMax(a + 2 * i, __float_as_uint((float)h.x));
    atomicMax(a + 2 * i + 1, __float_as_uint((float)h.y));
  }
}

// edge-parallel, K=4 dst-sorted edges per thread. Loop-interchanged fp16 dot2
// MLP: output-pair loop OUTER, edge loop INNER -> each weight s_load is reused
// across 4 edges (scalar traffic /256, stalls /4). Then per-thread segmented
// merge + fp16-packed wave segmented max + head-lane atomic flush (R7 logic).
__global__ __launch_bounds__(256) void edge_kernel(
    const uint2* __restrict__ xpk, const int4* __restrict__ erec,
    unsigned int* __restrict__ agg, const float* __restrict__ wg, int E) {
  const unsigned int* wp = (const unsigned int*)(wg + PKOFS);
  const float* bf = (const float*)wp;
  int t0 = (blockIdx.x * blockDim.x + threadIdx.x) * 4;
  int lane = threadIdx.x & 63;

  int4 rec[4];
  bool vld[4];
#pragma unroll
  for (int j = 0; j < 4; j++) {
    int e = t0 + j;
    vld[j] = e < E;
    rec[j] = erec[vld[j] ? e : 0];
  }
  uint2 xs[4];
#pragma unroll
  for (int j = 0; j < 4; j++) xs[j] = xpk[rec[j].x];

  h2 p01[4], p2[4], pea[4];
#pragma unroll
  for (int j = 0; j < 4; j++) {
    p01[j] = u2h(xs[j].x);
    p2[j] = u2h(xs[j].y);
    pea[j] = u2h((unsigned int)rec[j].z);
  }

  // ---- layer 1: pair-outer, edge-inner ----
  unsigned int m1[8][4];  // [k-pair][edge]
#pragma unroll
  for (int p = 0; p < 8; p++) {
    const int oA = 2 * p, oB = 2 * p + 1;
    h2 a0 = u2h(wp[oA]), a1 = u2h(wp[16 + oA]), a2 = u2h(wp[32 + oA]);
    h2 b0 = u2h(wp[oB]), b1 = u2h(wp[16 + oB]), b2 = u2h(wp[32 + oB]);
    float bA = bf[304 + oA], bB = bf[304 + oB];
#pragma unroll
    for (int j = 0; j < 4; j++) {
      float sA = DOT2(p01[j], a0, DOT2(p2[j], a1, DOT2(pea[j], a2, bA)));
      float sB = DOT2(p01[j], b0, DOT2(p2[j], b1, DOT2(pea[j], b2, bB)));
      m1[p][j] = h2u(__builtin_amdgcn_cvt_pkrtz(fmaxf(sA, 0.f), fmaxf(sB, 0.f)));
    }
  }

  // ---- layer 2: output-pair loop outer, edge loop inner ----
  unsigned int pk[4][16];  // [edge][feature-pair]
#pragma unroll
  for (int q = 0; q < 16; q++) {
    const int oA = 2 * q, oB = 2 * q + 1;
    float bA = bf[320 + oA], bB = bf[320 + oB];
#pragma unroll
    for (int j = 0; j < 4; j++) {
      float sA = bA, sB = bB;
#pragma unroll
      for (int k = 0; k < 8; k++) {
        sA = DOT2(u2h(m1[k][j]), u2h(wp[48 + oA * 8 + k]), sA);
        sB = DOT2(u2h(m1[k][j]), u2h(wp[48 + oB * 8 + k]), sB);
      }
      pk[j][q] = h2u(__builtin_amdgcn_cvt_pkrtz(fmaxf(sA, 0.f), fmaxf(sB, 0.f)));
    }
  }

  // ---- per-thread segmented merge ----
  unsigned int run[16];
  int cur = -1;
#pragma unroll
  for (int j = 0; j < 4; j++) {
    int dj = vld[j] ? rec[j].y : -1;
    if (j == 0) {
      cur = dj;
#pragma unroll
      for (int i = 0; i < 16; i++) run[i] = pk[0][i];
    } else if (dj == cur) {
#pragma unroll
      for (int i = 0; i < 16; i++)
        run[i] = h2u(__builtin_elementwise_max(u2h(run[i]), u2h(pk[j][i])));
    } else {
      if (cur >= 0) flushRun(agg, cur, run);
      cur = dj;
#pragma unroll
      for (int i = 0; i < 16; i++) run[i] = pk[j][i];
    }
  }

  // ---- wave segmented max over per-thread tail runs ----
#pragma unroll
  for (int off = 1; off < 64; off <<= 1) {
    int c2 = __shfl_down(cur, off, 64);
    unsigned int msk = ((lane + off < 64) && (c2 == cur) && (cur >= 0)) ? 0xFFFFFFFFu : 0u;
#pragma unroll
    for (int i = 0; i < 16; i++) {
      unsigned int v2 = __shfl_down(run[i], off, 64) & msk;
      run[i] = h2u(__builtin_elementwise_max(u2h(run[i]), u2h(v2)));
    }
  }
  int cprev = __shfl_up(cur, 1, 64);
  bool head = (cur >= 0) && (lane == 0 || cprev != cur);
  if (head) flushRun(agg, cur, run);
}

// node-parallel: read agg[nid][0..31], re-zero for next iter, node MLP + sigmoid.
__global__ __launch_bounds__(256) void node_kernel(
    const float* __restrict__ x, const float* __restrict__ cin,
    float* __restrict__ cout, uint2* __restrict__ xpk,
    float* __restrict__ outFinal, unsigned int* __restrict__ agg,
    const float* __restrict__ wg, int n) {
  int nid = blockIdx.x * blockDim.x + threadIdx.x;
  if (nid >= n) return;
  unsigned int* a = agg + (size_t)nid * 32;
  float av[32];
#pragma unroll
  for (int o = 0; o < 32; o += 4) {
    uint4 u = *(const uint4*)(a + o);
    av[o] = __uint_as_float(u.x);
    av[o + 1] = __uint_as_float(u.y);
    av[o + 2] = __uint_as_float(u.z);
    av[o + 3] = __uint_as_float(u.w);
    *(uint4*)(a + o) = make_uint4(0u, 0u, 0u, 0u);
  }
  float x0 = x[3 * nid], x1 = x[3 * nid + 1];
  float x2 = cin ? cin[nid] : x[3 * nid + 2];
  float h[16];
#pragma unroll
  for (int o = 0; o < 16; o++) {
    float sa = wg[1200 + o];  // b3
    sa = fmaf(wg[640 + o * 35 + 0], x0, sa);
    sa = fmaf(wg[640 + o * 35 + 1], x1, sa);
    sa = fmaf(wg[640 + o * 35 + 2], x2, sa);
#pragma unroll
    for (int k = 0; k < 32; k++) sa = fmaf(wg[640 + o * 35 + 3 + k], av[k], sa);
    h[o] = fmaxf(sa, 0.f);
  }
  float z = wg[1232];  // b4
#pragma unroll
  for (int k = 0; k < 16; k++) z = fmaf(wg[1216 + k], h[k], z);
  float comb = 1.f / (1.f + expf(-z));
  cout[nid] = comb;
  ((unsigned int*)xpk)[2 * nid + 1] = h2u(__builtin_amdgcn_cvt_pkrtz(comb, 0.f));
  if (outFinal) {
    outFinal[3 * nid] = x0;
    outFinal[3 * nid + 1] = x1;
    outFinal[3 * nid + 2] = comb;
  }
}

extern "C" void kernel_launch(void* const* d_in, const int* in_sizes, int n_in,
                              void* d_out, int out_size, void* d_ws, size_t ws_size,
                              hipStream_t stream) {
  const float* x = (const float*)d_in[0];
  const float* ea = (const float*)d_in[1];
  const int* eidx = (const int*)d_in[2];
  const int N = in_sizes[0] / 3;
  const int E = in_sizes[1] / 2;
  const int* src = eidx;
  const int* dst = eidx + E;
  const int P = (N + 1023) / 1024;

  // ---- workspace carve-up ----
  char* p = (char*)d_ws;
  size_t off = 0;
  auto alloc = [&](size_t bytes) -> char* {
    char* r = p + off;
    off = (off + bytes + 255) & ~(size_t)255;
    return r;
  };
  float* wbuf = (float*)alloc((size_t)(PKOFS + PKTOT) * 4);
  int* deg = (int*)alloc((size_t)N * 4);
  int* part = (int*)alloc((size_t)P * 4);
  int* cursor = (int*)alloc((size_t)N * 4);
  int4* erec = (int4*)alloc((size_t)E * 16);
  unsigned int* agg = (unsigned int*)alloc((size_t)N * 32 * 4);  // [N][32]
  uint2* xpk = (uint2*)alloc((size_t)N * 8);
  float* bufA = (float*)alloc((size_t)N * 4);
  float* bufB = (float*)alloc((size_t)N * 4);
  (void)ws_size;

  PrepArgs pa;
  for (int l = 0; l < 4; l++) {
    pa.wmu[l] = (const float*)d_in[3 + 6 * l + 0];
    pa.wrho[l] = (const float*)d_in[3 + 6 * l + 1];
    pa.bmu[l] = (const float*)d_in[3 + 6 * l + 2];
    pa.brho[l] = (const float*)d_in[3 + 6 * l + 3];
    pa.epsw[l] = (const float*)d_in[3 + 6 * l + 4];
    pa.epsb[l] = (const float*)d_in[3 + 6 * l + 5];
  }
  pa.out = wbuf;

  const int TB = 256;
  auto blocks = [&](int n) { return dim3((n + TB - 1) / TB); };

  zero_kernel<<<blocks(N), dim3(TB), 0, stream>>>(deg, N);
  prep_all_kernel<<<dim3(1), dim3(1024), 0, stream>>>(pa);
  count_kernel<<<blocks(E), dim3(TB), 0, stream>>>(dst, deg, E);
  scanA_kernel<<<dim3(P), dim3(1024), 0, stream>>>(deg, part, N);
  scanB_kernel<<<dim3(1), dim3(64), 0, stream>>>(part, P);
  scanC_kernel<<<dim3(P), dim3(1024), 0, stream>>>(deg, part, cursor, N);
  fill_kernel<<<blocks(E), dim3(TB), 0, stream>>>(src, dst, (const float2*)ea, cursor,
                                                  erec, E);
  int n4 = N * 8;  // N*32 uints as uint4
  init_kernel<<<blocks(n4), dim3(TB), 0, stream>>>(x, xpk, (uint4*)agg, N, n4);

  float* outp = (float*)d_out;
  int eb = (E + TB * 4 - 1) / (TB * 4);
  // iter 1
  edge_kernel<<<dim3(eb), dim3(TB), 0, stream>>>(xpk, erec, agg, wbuf, E);
  node_kernel<<<blocks(N), dim3(TB), 0, stream>>>(x, nullptr, bufA, xpk, nullptr, agg, wbuf, N);
  // iter 2
  edge_kernel<<<dim3(eb), dim3(TB), 0, stream>>>(xpk, erec, agg, wbuf, E);
  node_kernel<<<blocks(N), dim3(TB), 0, stream>>>(x, bufA, bufB, xpk, nullptr, agg, wbuf, N);
  // iter 3
  edge_kernel<<<dim3(eb), dim3(TB), 0, stream>>>(xpk, erec, agg, wbuf, E);
  node_kernel<<<blocks(N), dim3(TB), 0, stream>>>(x, bufB, bufA, xpk, outp, agg, wbuf, N);
}

// Round 9
// 891.653 us; speedup vs baseline: 1.6327x; 1.5798x over previous
//
#include <hip/hip_runtime.h>
#include <math.h>

// ---- weight buffer layout ----
// fp32 section (dwords 0..1232):
// W1[16][5]@0 b1@80 | W2[32][16]@96 b2@608 | W3[16][35]@640 b3@1200 | W4[16]@1216 b4@1232
// packed fp16 section (uint view at dword offset 1280):
// w1a[16]@0 (w[o5+0],w[o5+1]) | w1b[16]@16 (w[o5+2],0) | w1c[16]@32 (w[o5+3],w[o5+4])
// w2pk[32][8]@48 | b1f[16]@304 (fp32) | b2f[32]@320 (fp32)   -- total 352 dwords
#define WTOT  1233
#define PKOFS 1280
#define PKTOT 352

typedef __fp16 h2 __attribute__((ext_vector_type(2)));

__device__ __forceinline__ h2 u2h(unsigned int u) { return __builtin_bit_cast(h2, u); }
__device__ __forceinline__ unsigned int h2u(h2 h) { return __builtin_bit_cast(unsigned int, h); }
__device__ __forceinline__ unsigned int umax2(unsigned int a, unsigned int b) {
  return h2u(__builtin_elementwise_max(u2h(a), u2h(b)));
}
#define DOT2(a, b, c) __builtin_amdgcn_fdot2((a), (b), (c), false)

__device__ __forceinline__ float softplus_f(float x) {
  return fmaxf(x, 0.f) + log1pf(expf(-fabsf(x)));
}

struct PrepArgs {
  const float* wmu[4]; const float* wrho[4]; const float* epsw[4];
  const float* bmu[4]; const float* brho[4]; const float* epsb[4];
  float* out;
};

// single block 1024: sample all weights, then pack fp16 section
__global__ void prep_all_kernel(PrepArgs a) {
  const int wsz[4] = {80, 512, 560, 16};
  const int wof[4] = {0, 96, 640, 1216};
  const int bsz[4] = {16, 32, 16, 1};
  const int bof[4] = {80, 608, 1200, 1232};
  float* wg = a.out;
  int tid = threadIdx.x;
#pragma unroll
  for (int l = 0; l < 4; l++) {
    for (int i = tid; i < wsz[l]; i += 1024)
      wg[wof[l] + i] = a.wmu[l][i] + softplus_f(a.wrho[l][i]) * a.epsw[l][i];
    for (int i = tid; i < bsz[l]; i += 1024)
      wg[bof[l] + i] = a.bmu[l][i] + softplus_f(a.brho[l][i]) * a.epsb[l][i];
  }
  __syncthreads();
  unsigned int* wp = (unsigned int*)(wg + PKOFS);
  int t = tid;
  if (t < 16) {
    wp[t]      = h2u(h2{(__fp16)wg[t * 5 + 0], (__fp16)wg[t * 5 + 1]});
    wp[16 + t] = h2u(h2{(__fp16)wg[t * 5 + 2], (__fp16)0.f});
    wp[32 + t] = h2u(h2{(__fp16)wg[t * 5 + 3], (__fp16)wg[t * 5 + 4]});
    ((float*)wp)[304 + t] = wg[80 + t];
  }
  if (t < 32) {
    ((float*)wp)[320 + t] = wg[608 + t];
    for (int j = 0; j < 8; j++)
      wp[48 + t * 8 + j] =
          h2u(h2{(__fp16)wg[96 + t * 16 + 2 * j], (__fp16)wg[96 + t * 16 + 2 * j + 1]});
  }
}

__global__ void zero_kernel(int* __restrict__ p, int n) {
  int i = blockIdx.x * blockDim.x + threadIdx.x;
  if (i < n) p[i] = 0;
}

__global__ void count_kernel(const int* __restrict__ dst, int* __restrict__ deg, int E) {
  int e = blockIdx.x * blockDim.x + threadIdx.x;
  if (e < E) atomicAdd(&deg[dst[e]], 1);
}

// ---- 3-phase exclusive scan ----
__global__ void scanA_kernel(const int* __restrict__ deg, int* __restrict__ part, int n) {
  __shared__ int ws[16];
  int tid = threadIdx.x;
  int i = blockIdx.x * 1024 + tid;
  int v = (i < n) ? deg[i] : 0;
#pragma unroll
  for (int off = 32; off >= 1; off >>= 1) v += __shfl_down(v, off, 64);
  if ((tid & 63) == 0) ws[tid >> 6] = v;
  __syncthreads();
  if (tid == 0) {
    int s = 0;
#pragma unroll
    for (int k = 0; k < 16; k++) s += ws[k];
    part[blockIdx.x] = s;
  }
}

__global__ void scanB_kernel(int* __restrict__ part, int P) {
  int lane = threadIdx.x;  // single wave of 64
  int carry = 0;
  for (int base = 0; base < P; base += 64) {
    int i = base + lane;
    int v = (i < P) ? part[i] : 0;
    int x = v;
#pragma unroll
    for (int off = 1; off < 64; off <<= 1) {
      int t = __shfl_up(x, off, 64);
      if (lane >= off) x += t;
    }
    if (i < P) part[i] = carry + x - v;  // exclusive
    carry += __shfl(x, 63, 64);
  }
}

__global__ void scanC_kernel(const int* __restrict__ deg, const int* __restrict__ part,
                             int* __restrict__ cursor, int n) {
  __shared__ int wsum[16];
  __shared__ int woff[16];
  int tid = threadIdx.x, lane = tid & 63, wid = tid >> 6;
  int i = blockIdx.x * 1024 + tid;
  int v = (i < n) ? deg[i] : 0;
  int x = v;
#pragma unroll
  for (int off = 1; off < 64; off <<= 1) {
    int t = __shfl_up(x, off, 64);
    if (lane >= off) x += t;
  }
  if (lane == 63) wsum[wid] = x;
  __syncthreads();
  if (wid == 0) {
    int s = (lane < 16) ? wsum[lane] : 0;
#pragma unroll
    for (int off = 1; off < 16; off <<= 1) {
      int t = __shfl_up(s, off, 64);
      if (lane >= off) s += t;
    }
    if (lane < 16) woff[lane] = s - wsum[lane];
  }
  __syncthreads();
  if (i < n) cursor[i] = part[blockIdx.x] + woff[wid] + x - v;
}

// write packed edge records sorted by dst: (src, dst, pk(ea0,ea1), 0)
__global__ void fill_kernel(const int* __restrict__ src, const int* __restrict__ dst,
                            const float2* __restrict__ ea, int* __restrict__ cursor,
                            int4* __restrict__ erec, int E) {
  int e = blockIdx.x * blockDim.x + threadIdx.x;
  if (e >= E) return;
  int d = dst[e];
  int pos = atomicAdd(&cursor[d], 1);
  float2 a = ea[e];
  h2 ap = __builtin_amdgcn_cvt_pkrtz(a.x, a.y);
  erec[pos] = make_int4(src[e], d, (int)h2u(ap), 0);
}

// pack x to fp16 pairs
__global__ void xpack_kernel(const float* __restrict__ x, uint2* __restrict__ xpk, int n) {
  int i = blockIdx.x * blockDim.x + threadIdx.x;
  if (i < n) {
    h2 a = __builtin_amdgcn_cvt_pkrtz(x[3 * i], x[3 * i + 1]);
    h2 b = __builtin_amdgcn_cvt_pkrtz(x[3 * i + 2], 0.f);
    xpk[i] = make_uint2(h2u(a), h2u(b));
  }
}

// ATOMIC-FREE edge kernel. One thread per dst-sorted edge; window = 64 edges
// per wave. fp16 dot2 MLP -> wave segmented max -> head lanes classify runs:
//  complete in window -> direct 64B store to agg[d] (single writer)
//  continues left      -> left-partial slot of this window
//  continues right only-> right-partial slot
// Node kernel reassembles boundary runs from partials. No atomics, no agg init.
__global__ __launch_bounds__(256) void edge_kernel(
    const uint2* __restrict__ xpk, const int4* __restrict__ erec,
    unsigned int* __restrict__ agg,
    int* __restrict__ pdstL, uint4* __restrict__ pvalL,
    int* __restrict__ pdstR, uint4* __restrict__ pvalR,
    const float* __restrict__ wg, int E) {
  const unsigned int* wp = (const unsigned int*)(wg + PKOFS);
  const float* bf = (const float*)wp;
  int e = blockIdx.x * 256 + threadIdx.x;
  int lane = threadIdx.x & 63;
  int w = e >> 6;          // global window id
  int wbase = w << 6;
  bool vld = e < E;
  int4 rec = erec[vld ? e : (E - 1)];
  int d = vld ? rec.y : -1;
  uint2 xs = xpk[rec.x];

  // ---- edge MLP (fp16 dot2) ----
  h2 p01 = u2h(xs.x), p2v = u2h(xs.y), pea = u2h((unsigned int)rec.z);
  unsigned int m1[8];
#pragma unroll
  for (int p = 0; p < 8; p++) {
    const int oA = 2 * p, oB = 2 * p + 1;
    float sA = DOT2(p01, u2h(wp[oA]),
                DOT2(p2v, u2h(wp[16 + oA]),
                DOT2(pea, u2h(wp[32 + oA]), bf[304 + oA])));
    float sB = DOT2(p01, u2h(wp[oB]),
                DOT2(p2v, u2h(wp[16 + oB]),
                DOT2(pea, u2h(wp[32 + oB]), bf[304 + oB])));
    m1[p] = h2u(__builtin_amdgcn_cvt_pkrtz(fmaxf(sA, 0.f), fmaxf(sB, 0.f)));
  }
  unsigned int pk[16];
#pragma unroll
  for (int q = 0; q < 16; q++) {
    const int oA = 2 * q, oB = 2 * q + 1;
    float sA = bf[320 + oA], sB = bf[320 + oB];
#pragma unroll
    for (int k = 0; k < 8; k++) {
      sA = DOT2(u2h(m1[k]), u2h(wp[48 + oA * 8 + k]), sA);
      sB = DOT2(u2h(m1[k]), u2h(wp[48 + oB * 8 + k]), sB);
    }
    pk[q] = h2u(__builtin_amdgcn_cvt_pkrtz(fmaxf(sA, 0.f), fmaxf(sB, 0.f)));
  }

  // ---- neighbor dsts across window boundaries ----
  int dp = -2, dn = -2;
  if (lane == 0 && wbase > 0) dp = erec[wbase - 1].y;
  if (lane == 63 && wbase + 64 < E) dn = erec[wbase + 64].y;
  dp = __shfl(dp, 0, 64);
  dn = __shfl(dn, 63, 64);

  // ---- wave segmented max (each lane gets max from itself to segment end) ----
#pragma unroll
  for (int off = 1; off < 64; off <<= 1) {
    int d2 = __shfl_down(d, off, 64);
    unsigned int msk = ((lane + off < 64) && (d2 == d)) ? 0xFFFFFFFFu : 0u;
#pragma unroll
    for (int i = 0; i < 16; i++) {
      unsigned int v2 = __shfl_down(pk[i], off, 64) & msk;
      pk[i] = umax2(pk[i], v2);
    }
  }

  int dprev = __shfl_up(d, 1, 64);
  bool isHead = vld && (lane == 0 || d != dprev);
  unsigned long long hm = __ballot(isHead);
  if (isHead) {
    int lastHead = 63 - __builtin_clzll(hm);
    bool contL = (lane == 0) && (d == dp);
    bool contR = (lane == lastHead) && (d == dn);
    uint4 v0 = make_uint4(pk[0], pk[1], pk[2], pk[3]);
    uint4 v1 = make_uint4(pk[4], pk[5], pk[6], pk[7]);
    uint4 v2 = make_uint4(pk[8], pk[9], pk[10], pk[11]);
    uint4 v3 = make_uint4(pk[12], pk[13], pk[14], pk[15]);
    if (!contL && !contR) {
      uint4* a = (uint4*)(agg + (size_t)d * 16);
      a[0] = v0; a[1] = v1; a[2] = v2; a[3] = v3;
    } else if (contL) {
      pdstL[w] = d;
      pvalL[w * 4 + 0] = v0; pvalL[w * 4 + 1] = v1;
      pvalL[w * 4 + 2] = v2; pvalL[w * 4 + 3] = v3;
    } else {
      pdstR[w] = d;
      pvalR[w * 4 + 0] = v0; pvalR[w * 4 + 1] = v1;
      pvalR[w * 4 + 2] = v2; pvalR[w * 4 + 3] = v3;
    }
  }
}

__device__ __forceinline__ void max4(uint4& a, uint4 b) {
  a.x = umax2(a.x, b.x); a.y = umax2(a.y, b.y);
  a.z = umax2(a.z, b.z); a.w = umax2(a.w, b.w);
}

// node-parallel: reassemble aggregation (direct or from partials), node MLP.
__global__ __launch_bounds__(256) void node_kernel(
    const float* __restrict__ x, const float* __restrict__ cin,
    float* __restrict__ cout, uint2* __restrict__ xpk,
    float* __restrict__ outFinal, const unsigned int* __restrict__ agg,
    const int* __restrict__ deg, const int* __restrict__ cursor,
    const int* __restrict__ pdstL, const uint4* __restrict__ pvalL,
    const int* __restrict__ pdstR, const uint4* __restrict__ pvalR,
    const float* __restrict__ wg, int n) {
  int nid = blockIdx.x * blockDim.x + threadIdx.x;
  if (nid >= n) return;
  int dg = deg[nid];
  uint4 q0 = make_uint4(0u, 0u, 0u, 0u), q1 = q0, q2 = q0, q3 = q0;
  if (dg > 0) {
    int r1 = cursor[nid];
    int r0 = r1 - dg;
    int w0 = r0 >> 6, w1 = (r1 - 1) >> 6;
    if (w0 == w1) {
      const uint4* a = (const uint4*)(agg + (size_t)nid * 16);
      q0 = a[0]; q1 = a[1]; q2 = a[2]; q3 = a[3];
    } else {
      if (pdstR[w0] == nid) {
        q0 = pvalR[w0 * 4 + 0]; q1 = pvalR[w0 * 4 + 1];
        q2 = pvalR[w0 * 4 + 2]; q3 = pvalR[w0 * 4 + 3];
      }
      for (int w = w0 + 1; w <= w1; w++) {
        if (pdstL[w] == nid) {
          max4(q0, pvalL[w * 4 + 0]); max4(q1, pvalL[w * 4 + 1]);
          max4(q2, pvalL[w * 4 + 2]); max4(q3, pvalL[w * 4 + 3]);
        }
      }
    }
  }
  unsigned int pkv[16] = {q0.x, q0.y, q0.z, q0.w, q1.x, q1.y, q1.z, q1.w,
                          q2.x, q2.y, q2.z, q2.w, q3.x, q3.y, q3.z, q3.w};
  float av[32];
#pragma unroll
  for (int i = 0; i < 16; i++) {
    h2 h = u2h(pkv[i]);
    av[2 * i] = (float)h.x;
    av[2 * i + 1] = (float)h.y;
  }
  float x0 = x[3 * nid], x1 = x[3 * nid + 1];
  float x2 = cin ? cin[nid] : x[3 * nid + 2];
  float h[16];
#pragma unroll
  for (int o = 0; o < 16; o++) {
    float sa = wg[1200 + o];  // b3
    sa = fmaf(wg[640 + o * 35 + 0], x0, sa);
    sa = fmaf(wg[640 + o * 35 + 1], x1, sa);
    sa = fmaf(wg[640 + o * 35 + 2], x2, sa);
#pragma unroll
    for (int k = 0; k < 32; k++) sa = fmaf(wg[640 + o * 35 + 3 + k], av[k], sa);
    h[o] = fmaxf(sa, 0.f);
  }
  float z = wg[1232];  // b4
#pragma unroll
  for (int k = 0; k < 16; k++) z = fmaf(wg[1216 + k], h[k], z);
  float comb = 1.f / (1.f + expf(-z));
  cout[nid] = comb;
  ((unsigned int*)xpk)[2 * nid + 1] = h2u(__builtin_amdgcn_cvt_pkrtz(comb, 0.f));
  if (outFinal) {
    outFinal[3 * nid] = x0;
    outFinal[3 * nid + 1] = x1;
    outFinal[3 * nid + 2] = comb;
  }
}

extern "C" void kernel_launch(void* const* d_in, const int* in_sizes, int n_in,
                              void* d_out, int out_size, void* d_ws, size_t ws_size,
                              hipStream_t stream) {
  const float* x = (const float*)d_in[0];
  const float* ea = (const float*)d_in[1];
  const int* eidx = (const int*)d_in[2];
  const int N = in_sizes[0] / 3;
  const int E = in_sizes[1] / 2;
  const int* src = eidx;
  const int* dst = eidx + E;
  const int P = (N + 1023) / 1024;
  const int NW = (E + 63) / 64;  // windows

  // ---- workspace carve-up ----
  char* p = (char*)d_ws;
  size_t off = 0;
  auto alloc = [&](size_t bytes) -> char* {
    char* r = p + off;
    off = (off + bytes + 255) & ~(size_t)255;
    return r;
  };
  float* wbuf = (float*)alloc((size_t)(PKOFS + PKTOT) * 4);
  int* deg = (int*)alloc((size_t)N * 4);
  int* part = (int*)alloc((size_t)P * 4);
  int* cursor = (int*)alloc((size_t)N * 4);
  int4* erec = (int4*)alloc((size_t)E * 16);
  unsigned int* agg = (unsigned int*)alloc((size_t)N * 16 * 4);  // [N][16] fp16-pairs
  uint2* xpk = (uint2*)alloc((size_t)N * 8);
  int* pdstL = (int*)alloc((size_t)NW * 4);
  int* pdstR = (int*)alloc((size_t)NW * 4);
  uint4* pvalL = (uint4*)alloc((size_t)NW * 64);
  uint4* pvalR = (uint4*)alloc((size_t)NW * 64);
  float* bufA = (float*)alloc((size_t)N * 4);
  float* bufB = (float*)alloc((size_t)N * 4);
  (void)ws_size;

  PrepArgs pa;
  for (int l = 0; l < 4; l++) {
    pa.wmu[l] = (const float*)d_in[3 + 6 * l + 0];
    pa.wrho[l] = (const float*)d_in[3 + 6 * l + 1];
    pa.bmu[l] = (const float*)d_in[3 + 6 * l + 2];
    pa.brho[l] = (const float*)d_in[3 + 6 * l + 3];
    pa.epsw[l] = (const float*)d_in[3 + 6 * l + 4];
    pa.epsb[l] = (const float*)d_in[3 + 6 * l + 5];
  }
  pa.out = wbuf;

  const int TB = 256;
  auto blocks = [&](int n) { return dim3((n + TB - 1) / TB); };

  zero_kernel<<<blocks(N), dim3(TB), 0, stream>>>(deg, N);
  prep_all_kernel<<<dim3(1), dim3(1024), 0, stream>>>(pa);
  count_kernel<<<blocks(E), dim3(TB), 0, stream>>>(dst, deg, E);
  scanA_kernel<<<dim3(P), dim3(1024), 0, stream>>>(deg, part, N);
  scanB_kernel<<<dim3(1), dim3(64), 0, stream>>>(part, P);
  scanC_kernel<<<dim3(P), dim3(1024), 0, stream>>>(deg, part, cursor, N);
  fill_kernel<<<blocks(E), dim3(TB), 0, stream>>>(src, dst, (const float2*)ea, cursor,
                                                  erec, E);
  xpack_kernel<<<blocks(N), dim3(TB), 0, stream>>>(x, xpk, N);

  float* outp = (float*)d_out;
  int eb = (E + 255) / 256;
  // iter 1
  edge_kernel<<<dim3(eb), dim3(TB), 0, stream>>>(xpk, erec, agg, pdstL, pvalL, pdstR,
                                                 pvalR, wbuf, E);
  node_kernel<<<blocks(N), dim3(TB), 0, stream>>>(x, nullptr, bufA, xpk, nullptr, agg,
                                                  deg, cursor, pdstL, pvalL, pdstR,
                                                  pvalR, wbuf, N);
  // iter 2
  edge_kernel<<<dim3(eb), dim3(TB), 0, stream>>>(xpk, erec, agg, pdstL, pvalL, pdstR,
                                                 pvalR, wbuf, E);
  node_kernel<<<blocks(N), dim3(TB), 0, stream>>>(x, bufA, bufB, xpk, nullptr, agg,
                                                  deg, cursor, pdstL, pvalL, pdstR,
                                                  pvalR, wbuf, N);
  // iter 3
  edge_kernel<<<dim3(eb), dim3(TB), 0, stream>>>(xpk, erec, agg, pdstL, pvalL, pdstR,
                                                 pvalR, wbuf, E);
  node_kernel<<<blocks(N), dim3(TB), 0, stream>>>(x, bufB, bufA, xpk, outp, agg,
                                                  deg, cursor, pdstL, pvalL, pdstR,
                                                  pvalR, wbuf, N);
}

// Round 10
// 678.447 us; speedup vs baseline: 2.1458x; 1.3143x over previous
//
#include <hip/hip_runtime.h>
#include <math.h>

// ---- weight buffer layout ----
// fp32 section (dwords 0..1232):
// W1[16][5]@0 b1@80 | W2[32][16]@96 b2@608 | W3[16][35]@640 b3@1200 | W4[16]@1216 b4@1232
// packed fp16 section (uint view at dword offset 1280):
// w1a[16]@0 | w1b[16]@16 | w1c[16]@32 | w2pk[32][8]@48 | b1f[16]@304 | b2f[32]@320
#define WTOT  1233
#define PKOFS 1280
#define PKTOT 352

typedef __fp16 h2 __attribute__((ext_vector_type(2)));

__device__ __forceinline__ h2 u2h(unsigned int u) { return __builtin_bit_cast(h2, u); }
__device__ __forceinline__ unsigned int h2u(h2 h) { return __builtin_bit_cast(unsigned int, h); }
__device__ __forceinline__ unsigned int umax2(unsigned int a, unsigned int b) {
  return h2u(__builtin_elementwise_max(u2h(a), u2h(b)));
}
#define DOT2(a, b, c) __builtin_amdgcn_fdot2((a), (b), (c), false)

__device__ __forceinline__ float softplus_f(float x) {
  return fmaxf(x, 0.f) + log1pf(expf(-fabsf(x)));
}

struct PrepArgs {
  const float* wmu[4]; const float* wrho[4]; const float* epsw[4];
  const float* bmu[4]; const float* brho[4]; const float* epsb[4];
  float* out;
};

// single block 1024: sample all weights, then pack fp16 section
__global__ void prep_all_kernel(PrepArgs a) {
  const int wsz[4] = {80, 512, 560, 16};
  const int wof[4] = {0, 96, 640, 1216};
  const int bsz[4] = {16, 32, 16, 1};
  const int bof[4] = {80, 608, 1200, 1232};
  float* wg = a.out;
  int tid = threadIdx.x;
#pragma unroll
  for (int l = 0; l < 4; l++) {
    for (int i = tid; i < wsz[l]; i += 1024)
      wg[wof[l] + i] = a.wmu[l][i] + softplus_f(a.wrho[l][i]) * a.epsw[l][i];
    for (int i = tid; i < bsz[l]; i += 1024)
      wg[bof[l] + i] = a.bmu[l][i] + softplus_f(a.brho[l][i]) * a.epsb[l][i];
  }
  __syncthreads();
  unsigned int* wp = (unsigned int*)(wg + PKOFS);
  int t = tid;
  if (t < 16) {
    wp[t]      = h2u(h2{(__fp16)wg[t * 5 + 0], (__fp16)wg[t * 5 + 1]});
    wp[16 + t] = h2u(h2{(__fp16)wg[t * 5 + 2], (__fp16)0.f});
    wp[32 + t] = h2u(h2{(__fp16)wg[t * 5 + 3], (__fp16)wg[t * 5 + 4]});
    ((float*)wp)[304 + t] = wg[80 + t];
  }
  if (t < 32) {
    ((float*)wp)[320 + t] = wg[608 + t];
    for (int j = 0; j < 8; j++)
      wp[48 + t * 8 + j] =
          h2u(h2{(__fp16)wg[96 + t * 16 + 2 * j], (__fp16)wg[96 + t * 16 + 2 * j + 1]});
  }
}

__global__ void zero_kernel(int* __restrict__ p, int n) {
  int i = blockIdx.x * blockDim.x + threadIdx.x;
  if (i < n) p[i] = 0;
}

// per-block LDS histogram of dst buckets (bucket = dst>>7), flush to bucketCur
__global__ __launch_bounds__(1024) void bhist_kernel(const int* __restrict__ dst,
                                                     int* __restrict__ bucketCur,
                                                     int E, int NBUCK) {
  __shared__ int h[1024];
  int tid = threadIdx.x;
  for (int i = tid; i < NBUCK; i += 1024) h[i] = 0;
  __syncthreads();
  int base = blockIdx.x * 8192;
#pragma unroll
  for (int r = 0; r < 8; r++) {
    int e = base + r * 1024 + tid;
    if (e < E) atomicAdd(&h[dst[e] >> 7], 1);
  }
  __syncthreads();
  for (int i = tid; i < NBUCK; i += 1024) {
    int c = h[i];
    if (c) atomicAdd(&bucketCur[i], c);
  }
}

// single-block exclusive scan over NBUCK (<=1024) counts held in bucketCur;
// writes bucketOff[0..NBUCK] and re-seeds bucketCur with the exclusive offsets
__global__ __launch_bounds__(1024) void scanBk_kernel(int* __restrict__ bucketCur,
                                                      int* __restrict__ bucketOff,
                                                      int NBUCK) {
  __shared__ int wsum[16];
  __shared__ int woff[16];
  int tid = threadIdx.x, lane = tid & 63, wid = tid >> 6;
  int v = (tid < NBUCK) ? bucketCur[tid] : 0;
  int x = v;
#pragma unroll
  for (int off = 1; off < 64; off <<= 1) {
    int t = __shfl_up(x, off, 64);
    if (lane >= off) x += t;
  }
  if (lane == 63) wsum[wid] = x;
  __syncthreads();
  if (wid == 0) {
    int s = (lane < 16) ? wsum[lane] : 0;
#pragma unroll
    for (int off = 1; off < 16; off <<= 1) {
      int t = __shfl_up(s, off, 64);
      if (lane >= off) s += t;
    }
    if (lane < 16) woff[lane] = s - wsum[lane];
  }
  __syncthreads();
  int excl = woff[wid] + x - v;
  if (tid < NBUCK) {
    bucketOff[tid] = excl;
    bucketCur[tid] = excl;
    if (tid == NBUCK - 1) bucketOff[NBUCK] = excl + v;
  }
}

// partition edges into bucket regions: per-block LDS hist -> global reserve ->
// LDS-cursor append. Writes SoA (bsrc, bea, bdst) with ~NBUCK hot frontiers.
__global__ __launch_bounds__(1024) void part_kernel(
    const int* __restrict__ src, const int* __restrict__ dst,
    const float2* __restrict__ ea, int* __restrict__ bucketCur,
    int* __restrict__ bsrc, unsigned int* __restrict__ bea,
    int* __restrict__ bdst, int E, int NBUCK) {
  __shared__ int h[1024];
  int tid = threadIdx.x;
  for (int i = tid; i < NBUCK; i += 1024) h[i] = 0;
  __syncthreads();
  int base = blockIdx.x * 4096;
  int d[4], s[4];
  unsigned int a[4];
  bool v[4];
#pragma unroll
  for (int j = 0; j < 4; j++) {
    int e = base + j * 1024 + tid;
    v[j] = e < E;
    if (v[j]) {
      d[j] = dst[e];
      s[j] = src[e];
      float2 t = ea[e];
      a[j] = h2u(__builtin_amdgcn_cvt_pkrtz(t.x, t.y));
      atomicAdd(&h[d[j] >> 7], 1);
    }
  }
  __syncthreads();
  for (int i = tid; i < NBUCK; i += 1024) {
    int c = h[i];
    h[i] = c ? atomicAdd(&bucketCur[i], c) : 0;
  }
  __syncthreads();
#pragma unroll
  for (int j = 0; j < 4; j++) {
    if (v[j]) {
      int pos = atomicAdd(&h[d[j] >> 7], 1);
      bsrc[pos] = s[j];
      bdst[pos] = d[j];
      bea[pos] = a[j];
    }
  }
}

// per-bucket degree via LDS histogram; coalesced non-atomic deg write
__global__ __launch_bounds__(256) void deg_kernel(const int* __restrict__ bdst,
                                                  const int* __restrict__ bucketOff,
                                                  int* __restrict__ deg, int N) {
  __shared__ int cnt[128];
  int b = blockIdx.x, tid = threadIdx.x;
  if (tid < 128) cnt[tid] = 0;
  __syncthreads();
  int e0 = bucketOff[b], e1 = bucketOff[b + 1];
  for (int i = e0 + tid; i < e1; i += 256) atomicAdd(&cnt[bdst[i] & 127], 1);
  __syncthreads();
  int node = b * 128 + tid;
  if (tid < 128 && node < N) deg[node] = cnt[tid];
}

// ---- 3-phase exclusive scan over deg -> cursor (start positions) ----
__global__ void scanA_kernel(const int* __restrict__ deg, int* __restrict__ part, int n) {
  __shared__ int ws[16];
  int tid = threadIdx.x;
  int i = blockIdx.x * 1024 + tid;
  int v = (i < n) ? deg[i] : 0;
#pragma unroll
  for (int off = 32; off >= 1; off >>= 1) v += __shfl_down(v, off, 64);
  if ((tid & 63) == 0) ws[tid >> 6] = v;
  __syncthreads();
  if (tid == 0) {
    int s = 0;
#pragma unroll
    for (int k = 0; k < 16; k++) s += ws[k];
    part[blockIdx.x] = s;
  }
}

__global__ void scanB_kernel(int* __restrict__ part, int P) {
  int lane = threadIdx.x;
  int carry = 0;
  for (int base = 0; base < P; base += 64) {
    int i = base + lane;
    int v = (i < P) ? part[i] : 0;
    int x = v;
#pragma unroll
    for (int off = 1; off < 64; off <<= 1) {
      int t = __shfl_up(x, off, 64);
      if (lane >= off) x += t;
    }
    if (i < P) part[i] = carry + x - v;
    carry += __shfl(x, 63, 64);
  }
}

__global__ void scanC_kernel(const int* __restrict__ deg, const int* __restrict__ part,
                             int* __restrict__ cursor, int n) {
  __shared__ int wsum[16];
  __shared__ int woff[16];
  int tid = threadIdx.x, lane = tid & 63, wid = tid >> 6;
  int i = blockIdx.x * 1024 + tid;
  int v = (i < n) ? deg[i] : 0;
  int x = v;
#pragma unroll
  for (int off = 1; off < 64; off <<= 1) {
    int t = __shfl_up(x, off, 64);
    if (lane >= off) x += t;
  }
  if (lane == 63) wsum[wid] = x;
  __syncthreads();
  if (wid == 0) {
    int s = (lane < 16) ? wsum[lane] : 0;
#pragma unroll
    for (int off = 1; off < 16; off <<= 1) {
      int t = __shfl_up(s, off, 64);
      if (lane >= off) s += t;
    }
    if (lane < 16) woff[lane] = s - wsum[lane];
  }
  __syncthreads();
  if (i < n) cursor[i] = part[blockIdx.x] + woff[wid] + x - v;
}

// per-bucket final scatter: LDS cursors seeded from global start-cursor;
// writes AoS records into the bucket's contiguous (L2-hot) final region.
__global__ __launch_bounds__(256) void scat_kernel(
    const int* __restrict__ bsrc, const unsigned int* __restrict__ bea,
    const int* __restrict__ bdst, const int* __restrict__ bucketOff,
    const int* __restrict__ cursor, int4* __restrict__ erec, int N) {
  __shared__ int lcur[128];
  int b = blockIdx.x, tid = threadIdx.x;
  int node = b * 128 + tid;
  if (tid < 128) lcur[tid] = (node < N) ? cursor[node] : 0;
  __syncthreads();
  int e0 = bucketOff[b], e1 = bucketOff[b + 1];
  for (int i = e0 + tid; i < e1; i += 256) {
    int d = bdst[i];
    int pos = atomicAdd(&lcur[d & 127], 1);
    erec[pos] = make_int4(bsrc[i], d, (int)bea[i], 0);
  }
}

// pack x to fp16 pairs
__global__ void xpack_kernel(const float* __restrict__ x, uint2* __restrict__ xpk, int n) {
  int i = blockIdx.x * blockDim.x + threadIdx.x;
  if (i < n) {
    h2 a = __builtin_amdgcn_cvt_pkrtz(x[3 * i], x[3 * i + 1]);
    h2 b = __builtin_amdgcn_cvt_pkrtz(x[3 * i + 2], 0.f);
    xpk[i] = make_uint2(h2u(a), h2u(b));
  }
}

// ATOMIC-FREE edge kernel (R9): window=64 edges/wave, fp16 dot2 MLP, wave
// segmented max, head lanes: complete run -> direct store; boundary -> partial.
__global__ __launch_bounds__(256) void edge_kernel(
    const uint2* __restrict__ xpk, const int4* __restrict__ erec,
    unsigned int* __restrict__ agg,
    int* __restrict__ pdstL, uint4* __restrict__ pvalL,
    int* __restrict__ pdstR, uint4* __restrict__ pvalR,
    const float* __restrict__ wg, int E) {
  const unsigned int* wp = (const unsigned int*)(wg + PKOFS);
  const float* bf = (const float*)wp;
  int e = blockIdx.x * 256 + threadIdx.x;
  int lane = threadIdx.x & 63;
  int w = e >> 6;
  int wbase = w << 6;
  bool vld = e < E;
  int4 rec = erec[vld ? e : (E - 1)];
  int d = vld ? rec.y : -1;
  uint2 xs = xpk[rec.x];

  h2 p01 = u2h(xs.x), p2v = u2h(xs.y), pea = u2h((unsigned int)rec.z);
  unsigned int m1[8];
#pragma unroll
  for (int p = 0; p < 8; p++) {
    const int oA = 2 * p, oB = 2 * p + 1;
    float sA = DOT2(p01, u2h(wp[oA]),
                DOT2(p2v, u2h(wp[16 + oA]),
                DOT2(pea, u2h(wp[32 + oA]), bf[304 + oA])));
    float sB = DOT2(p01, u2h(wp[oB]),
                DOT2(p2v, u2h(wp[16 + oB]),
                DOT2(pea, u2h(wp[32 + oB]), bf[304 + oB])));
    m1[p] = h2u(__builtin_amdgcn_cvt_pkrtz(fmaxf(sA, 0.f), fmaxf(sB, 0.f)));
  }
  unsigned int pk[16];
#pragma unroll
  for (int q = 0; q < 16; q++) {
    const int oA = 2 * q, oB = 2 * q + 1;
    float sA = bf[320 + oA], sB = bf[320 + oB];
#pragma unroll
    for (int k = 0; k < 8; k++) {
      sA = DOT2(u2h(m1[k]), u2h(wp[48 + oA * 8 + k]), sA);
      sB = DOT2(u2h(m1[k]), u2h(wp[48 + oB * 8 + k]), sB);
    }
    pk[q] = h2u(__builtin_amdgcn_cvt_pkrtz(fmaxf(sA, 0.f), fmaxf(sB, 0.f)));
  }

  int dp = -2, dn = -2;
  if (lane == 0 && wbase > 0) dp = erec[wbase - 1].y;
  if (lane == 63 && wbase + 64 < E) dn = erec[wbase + 64].y;
  dp = __shfl(dp, 0, 64);
  dn = __shfl(dn, 63, 64);

#pragma unroll
  for (int off = 1; off < 64; off <<= 1) {
    int d2 = __shfl_down(d, off, 64);
    unsigned int msk = ((lane + off < 64) && (d2 == d)) ? 0xFFFFFFFFu : 0u;
#pragma unroll
    for (int i = 0; i < 16; i++) {
      unsigned int v2 = __shfl_down(pk[i], off, 64) & msk;
      pk[i] = umax2(pk[i], v2);
    }
  }

  int dprev = __shfl_up(d, 1, 64);
  bool isHead = vld && (lane == 0 || d != dprev);
  unsigned long long hm = __ballot(isHead);
  if (isHead) {
    int lastHead = 63 - __builtin_clzll(hm);
    bool contL = (lane == 0) && (d == dp);
    bool contR = (lane == lastHead) && (d == dn);
    uint4 v0 = make_uint4(pk[0], pk[1], pk[2], pk[3]);
    uint4 v1 = make_uint4(pk[4], pk[5], pk[6], pk[7]);
    uint4 v2 = make_uint4(pk[8], pk[9], pk[10], pk[11]);
    uint4 v3 = make_uint4(pk[12], pk[13], pk[14], pk[15]);
    if (!contL && !contR) {
      uint4* a = (uint4*)(agg + (size_t)d * 16);
      a[0] = v0; a[1] = v1; a[2] = v2; a[3] = v3;
    } else if (contL) {
      pdstL[w] = d;
      pvalL[w * 4 + 0] = v0; pvalL[w * 4 + 1] = v1;
      pvalL[w * 4 + 2] = v2; pvalL[w * 4 + 3] = v3;
    } else {
      pdstR[w] = d;
      pvalR[w * 4 + 0] = v0; pvalR[w * 4 + 1] = v1;
      pvalR[w * 4 + 2] = v2; pvalR[w * 4 + 3] = v3;
    }
  }
}

__device__ __forceinline__ void max4(uint4& a, uint4 b) {
  a.x = umax2(a.x, b.x); a.y = umax2(a.y, b.y);
  a.z = umax2(a.z, b.z); a.w = umax2(a.w, b.w);
}

// node-parallel: reassemble aggregation, node MLP. cursor = START positions.
__global__ __launch_bounds__(256) void node_kernel(
    const float* __restrict__ x, const float* __restrict__ cin,
    float* __restrict__ cout, uint2* __restrict__ xpk,
    float* __restrict__ outFinal, const unsigned int* __restrict__ agg,
    const int* __restrict__ deg, const int* __restrict__ cursor,
    const int* __restrict__ pdstL, const uint4* __restrict__ pvalL,
    const int* __restrict__ pdstR, const uint4* __restrict__ pvalR,
    const float* __restrict__ wg, int n) {
  int nid = blockIdx.x * blockDim.x + threadIdx.x;
  if (nid >= n) return;
  int dg = deg[nid];
  uint4 q0 = make_uint4(0u, 0u, 0u, 0u), q1 = q0, q2 = q0, q3 = q0;
  if (dg > 0) {
    int r0 = cursor[nid];
    int r1 = r0 + dg;
    int w0 = r0 >> 6, w1 = (r1 - 1) >> 6;
    if (w0 == w1) {
      const uint4* a = (const uint4*)(agg + (size_t)nid * 16);
      q0 = a[0]; q1 = a[1]; q2 = a[2]; q3 = a[3];
    } else {
      if (pdstR[w0] == nid) {
        q0 = pvalR[w0 * 4 + 0]; q1 = pvalR[w0 * 4 + 1];
        q2 = pvalR[w0 * 4 + 2]; q3 = pvalR[w0 * 4 + 3];
      }
      for (int w = w0 + 1; w <= w1; w++) {
        if (pdstL[w] == nid) {
          max4(q0, pvalL[w * 4 + 0]); max4(q1, pvalL[w * 4 + 1]);
          max4(q2, pvalL[w * 4 + 2]); max4(q3, pvalL[w * 4 + 3]);
        }
      }
    }
  }
  unsigned int pkv[16] = {q0.x, q0.y, q0.z, q0.w, q1.x, q1.y, q1.z, q1.w,
                          q2.x, q2.y, q2.z, q2.w, q3.x, q3.y, q3.z, q3.w};
  float av[32];
#pragma unroll
  for (int i = 0; i < 16; i++) {
    h2 h = u2h(pkv[i]);
    av[2 * i] = (float)h.x;
    av[2 * i + 1] = (float)h.y;
  }
  float x0 = x[3 * nid], x1 = x[3 * nid + 1];
  float x2 = cin ? cin[nid] : x[3 * nid + 2];
  float h[16];
#pragma unroll
  for (int o = 0; o < 16; o++) {
    float sa = wg[1200 + o];
    sa = fmaf(wg[640 + o * 35 + 0], x0, sa);
    sa = fmaf(wg[640 + o * 35 + 1], x1, sa);
    sa = fmaf(wg[640 + o * 35 + 2], x2, sa);
#pragma unroll
    for (int k = 0; k < 32; k++) sa = fmaf(wg[640 + o * 35 + 3 + k], av[k], sa);
    h[o] = fmaxf(sa, 0.f);
  }
  float z = wg[1232];
#pragma unroll
  for (int k = 0; k < 16; k++) z = fmaf(wg[1216 + k], h[k], z);
  float comb = 1.f / (1.f + expf(-z));
  cout[nid] = comb;
  ((unsigned int*)xpk)[2 * nid + 1] = h2u(__builtin_amdgcn_cvt_pkrtz(comb, 0.f));
  if (outFinal) {
    outFinal[3 * nid] = x0;
    outFinal[3 * nid + 1] = x1;
    outFinal[3 * nid + 2] = comb;
  }
}

extern "C" void kernel_launch(void* const* d_in, const int* in_sizes, int n_in,
                              void* d_out, int out_size, void* d_ws, size_t ws_size,
                              hipStream_t stream) {
  const float* x = (const float*)d_in[0];
  const float* ea = (const float*)d_in[1];
  const int* eidx = (const int*)d_in[2];
  const int N = in_sizes[0] / 3;
  const int E = in_sizes[1] / 2;
  const int* src = eidx;
  const int* dst = eidx + E;
  const int P = (N + 1023) / 1024;
  const int NW = (E + 63) / 64;      // windows
  const int NBUCK = (N + 127) >> 7;  // dst buckets (<=1024 for N<=131072)

  // ---- workspace carve-up ----
  char* p = (char*)d_ws;
  size_t off = 0;
  auto alloc = [&](size_t bytes) -> char* {
    char* r = p + off;
    off = (off + bytes + 255) & ~(size_t)255;
    return r;
  };
  float* wbuf = (float*)alloc((size_t)(PKOFS + PKTOT) * 4);
  int* deg = (int*)alloc((size_t)N * 4);
  int* part = (int*)alloc((size_t)P * 4);
  int* cursor = (int*)alloc((size_t)N * 4);
  int* bucketOff = (int*)alloc(((size_t)NBUCK + 1) * 4);
  int* bucketCur = (int*)alloc((size_t)NBUCK * 4);
  int4* erec = (int4*)alloc((size_t)E * 16);
  // UNION region: build-phase SoA (bsrc|bea|bdst, 12B/edge) aliased with
  // run-phase arrays (agg, xpk, partials, bufA/B ~15MB < E*12B)
  char* uni = alloc((size_t)E * 12);
  int* bsrc = (int*)uni;
  unsigned int* bea = (unsigned int*)(uni + (size_t)E * 4);
  int* bdst = (int*)(uni + (size_t)E * 8);
  size_t uoff = 0;
  auto ualloc = [&](size_t bytes) -> char* {
    char* r = uni + uoff;
    uoff = (uoff + bytes + 255) & ~(size_t)255;
    return r;
  };
  unsigned int* agg = (unsigned int*)ualloc((size_t)N * 16 * 4);
  uint2* xpk = (uint2*)ualloc((size_t)N * 8);
  int* pdstL = (int*)ualloc((size_t)NW * 4);
  int* pdstR = (int*)ualloc((size_t)NW * 4);
  uint4* pvalL = (uint4*)ualloc((size_t)NW * 64);
  uint4* pvalR = (uint4*)ualloc((size_t)NW * 64);
  float* bufA = (float*)ualloc((size_t)N * 4);
  float* bufB = (float*)ualloc((size_t)N * 4);
  (void)ws_size;

  PrepArgs pa;
  for (int l = 0; l < 4; l++) {
    pa.wmu[l] = (const float*)d_in[3 + 6 * l + 0];
    pa.wrho[l] = (const float*)d_in[3 + 6 * l + 1];
    pa.bmu[l] = (const float*)d_in[3 + 6 * l + 2];
    pa.brho[l] = (const float*)d_in[3 + 6 * l + 3];
    pa.epsw[l] = (const float*)d_in[3 + 6 * l + 4];
    pa.epsb[l] = (const float*)d_in[3 + 6 * l + 5];
  }
  pa.out = wbuf;

  const int TB = 256;
  auto blocks = [&](int n) { return dim3((n + TB - 1) / TB); };

  prep_all_kernel<<<dim3(1), dim3(1024), 0, stream>>>(pa);
  zero_kernel<<<blocks(NBUCK), dim3(TB), 0, stream>>>(bucketCur, NBUCK);
  bhist_kernel<<<dim3((E + 8191) / 8192), dim3(1024), 0, stream>>>(dst, bucketCur, E, NBUCK);
  scanBk_kernel<<<dim3(1), dim3(1024), 0, stream>>>(bucketCur, bucketOff, NBUCK);
  part_kernel<<<dim3((E + 4095) / 4096), dim3(1024), 0, stream>>>(
      src, dst, (const float2*)ea, bucketCur, bsrc, bea, bdst, E, NBUCK);
  deg_kernel<<<dim3(NBUCK), dim3(TB), 0, stream>>>(bdst, bucketOff, deg, N);
  scanA_kernel<<<dim3(P), dim3(1024), 0, stream>>>(deg, part, N);
  scanB_kernel<<<dim3(1), dim3(64), 0, stream>>>(part, P);
  scanC_kernel<<<dim3(P), dim3(1024), 0, stream>>>(deg, part, cursor, N);
  scat_kernel<<<dim3(NBUCK), dim3(TB), 0, stream>>>(bsrc, bea, bdst, bucketOff, cursor,
                                                    erec, N);
  xpack_kernel<<<blocks(N), dim3(TB), 0, stream>>>(x, xpk, N);

  float* outp = (float*)d_out;
  int eb = (E + 255) / 256;
  // iter 1
  edge_kernel<<<dim3(eb), dim3(TB), 0, stream>>>(xpk, erec, agg, pdstL, pvalL, pdstR,
                                                 pvalR, wbuf, E);
  node_kernel<<<blocks(N), dim3(TB), 0, stream>>>(x, nullptr, bufA, xpk, nullptr, agg,
                                                  deg, cursor, pdstL, pvalL, pdstR,
                                                  pvalR, wbuf, N);
  // iter 2
  edge_kernel<<<dim3(eb), dim3(TB), 0, stream>>>(xpk, erec, agg, pdstL, pvalL, pdstR,
                                                 pvalR, wbuf, E);
  node_kernel<<<blocks(N), dim3(TB), 0, stream>>>(x, bufA, bufB, xpk, nullptr, agg,
                                                  deg, cursor, pdstL, pvalL, pdstR,
                                                  pvalR, wbuf, N);
  // iter 3
  edge_kernel<<<dim3(eb), dim3(TB), 0, stream>>>(xpk, erec, agg, pdstL, pvalL, pdstR,
                                                 pvalR, wbuf, E);
  node_kernel<<<blocks(N), dim3(TB), 0, stream>>>(x, bufB, bufA, xpk, outp, agg,
                                                  deg, cursor, pdstL, pvalL, pdstR,
                                                  pvalR, wbuf, N);
}